// Round 18
// baseline (35.224 us; speedup 1.0000x reference)
//
#include <hip/hip_runtime.h>
#include <cstddef>

// Hyperbolic supervised contrastive loss, fused, MFMA bf16 Gram, symmetric.
// G ~= bf16(F) bf16(F)^T (validated r12-r17, absmax 0.0 vs threshold 9.4e-2).
// logits_max cancels (softmax shift invariance).
// r16/r17 lesson (measured): launch_bounds waves-arg is a VGPR cap -- (256,8)
// = 64 VGPR -> 143 MB scratch spill; (256,4) = 128 VGPR -> spill-free, 34.6us.
// NO GLOBAL ATOMICS in gram: wedge gives every (split,row) a unique writer:
//   entry (s, r), br=r/64:  br<s -> block (br,s) row-side
//                           br>s -> block (s,br) col-side
//                           br==s -> diagonal block stores row+col sum
// 64x64 tiles, triangular wedge bi<=bj (nt=64, 2080 blocks), LDS ~20 KB.
// B-tile 16B-chunk XOR swizzle (c ^= row&7), linear dest + pre-swizzled src.
// Finalize: ONE kernel (16 blocks + done-counter; last block does the final
// 16-wide reduce). r14's counter pattern was correct -- its cost was 1056
// threadfences; 16 are free. Saves one graph node (~3-5us).
// exp(logit) = ratio^20 via 5 mults; logit = 20*ln2*log2(ratio).

typedef __bf16 bf16x8 __attribute__((ext_vector_type(8)));
typedef __bf16 bf16x4 __attribute__((ext_vector_type(4)));
typedef float  f32x4  __attribute__((ext_vector_type(4)));

#define C_CONST 0.01f
#define RATIO_MIN 5.000025e-06f           // ratio at clamp 1-1e-5
#define LOGIT_SCALE 13.86294361119890619f // 20*ln(2)
#define TEMP 0.5f
#define LN2 0.69314718055994530942f
constexpr int DD = 128;
constexpr int NSPLIT = 64;                // = nt
constexpr int FBLK = 16;

// bf16 convert + row squared-norms + zero done-counter. 8 rows/block.
__global__ __launch_bounds__(256) void prep_kernel(
    const float* __restrict__ F, __bf16* __restrict__ Fh, float* __restrict__ sq,
    unsigned int* __restrict__ cnt) {
  const int tid = threadIdx.x;
  const int lane = tid & 31;
  const int row = blockIdx.x * 8 + (tid >> 5);
  if (blockIdx.x == 0 && tid == 0) *cnt = 0u;
  const float4 v = *reinterpret_cast<const float4*>(F + (size_t)row * DD + lane * 4);
  float s = v.x * v.x + v.y * v.y + v.z * v.z + v.w * v.w;
  bf16x4 h;
  h[0] = (__bf16)v.x; h[1] = (__bf16)v.y; h[2] = (__bf16)v.z; h[3] = (__bf16)v.w;
  *reinterpret_cast<bf16x4*>(Fh + (size_t)row * DD + lane * 4) = h;
#pragma unroll
  for (int off = 1; off < 32; off <<= 1) s += __shfl_xor(s, off);
  if (lane == 0) sq[row] = s;
}

// 64x64 tile; 4 waves, wave w owns rows row0..row0+15 (1 row-frag x 4 col-frags).
// C/D layout (verified m89): value r of frag fj at
// row = row0 + lg*4 + r, col = col0 + fj*16 + ln.
__global__ __launch_bounds__(256, 4) void gram_kernel(
    const __bf16* __restrict__ Fh,
    const float* __restrict__ sq, const int* __restrict__ labels,
    float* __restrict__ dpart, float* __restrict__ ppart, float* __restrict__ npart,
    int B, int nt) {
  __shared__ __bf16 Bs[64 * 128];           // 16 KB B-tile, chunk-XOR swizzle
  __shared__ float colAcc[4][3][64];        // per-wave col-side slices (3 KB)
  __shared__ float rowAcc[4][3][16];        // per-wave row-side slices (768 B)
  char* BsB = reinterpret_cast<char*>(Bs);

  const int tid = threadIdx.x;
  const int l  = tid & 63;
  const int w  = tid >> 6;
  const int lg = l >> 4, ln = l & 15;
  const int lx = ln & 7;

  // triangular decode: block t -> (bi, bj), bi <= bj. S(bi) = bi*nt - bi(bi-1)/2
  const int t = blockIdx.x;
  int bi = (int)((2 * nt + 1 - sqrtf((float)((2 * nt + 1) * (2 * nt + 1) - 8 * t))) * 0.5f);
  while ((bi + 1) * nt - ((bi + 1) * bi) / 2 <= t) ++bi;
  while (bi * nt - (bi * (bi - 1)) / 2 > t) --bi;
  const int bj = bi + (t - (bi * nt - (bi * (bi - 1)) / 2));

  const int row0 = bi * 64 + w * 16;
  const int col0 = bj * 64;

  // --- stage B tile (64 rows x 128 dims) into LDS: linear dest, pre-swizzled src
  // LDS chunk k (16B) of row r holds global chunk ((k&15) ^ (r&7)) of row r.
#pragma unroll
  for (int j = 0; j < 4; ++j) {
    const int k = tid + j * 256;            // chunk id 0..1023
    const int row = k >> 4;
    const int cc = (k & 15) ^ (row & 7);
    bf16x8 v = *reinterpret_cast<const bf16x8*>(Fh + (size_t)(col0 + row) * DD + cc * 8);
    *reinterpret_cast<bf16x8*>(BsB + (size_t)k * 16) = v;
  }

  // --- A fragments to regs (16 VGPR)
  const __bf16* Ahp = Fh + (size_t)(row0 + ln) * DD + lg * 8;
  bf16x8 ah[4];
#pragma unroll
  for (int kt = 0; kt < 4; ++kt)
    ah[kt] = *reinterpret_cast<const bf16x8*>(Ahp + kt * 32);

  // --- row/col metadata hoisted pre-barrier
  float si[4]; int li[4];
#pragma unroll
  for (int r = 0; r < 4; ++r) {
    const int row = row0 + lg * 4 + r;
    si[r] = sq[row];
    li[r] = labels[row];
  }
  float sqj[4]; int labj[4];
#pragma unroll
  for (int fj = 0; fj < 4; ++fj) {
    sqj[fj]  = sq[col0 + fj * 16 + ln];
    labj[fj] = labels[col0 + fj * 16 + ln];
  }

  __syncthreads();

  float dacc[4] = {}, pacc[4] = {}, nacc[4] = {};

#pragma unroll
  for (int fj = 0; fj < 4; ++fj) {
    // 4 ds_read_b128 (swizzled)
    const int rbase = (fj * 16 + ln) * 256;
    bf16x8 bh[4];
#pragma unroll
    for (int kt = 0; kt < 4; ++kt)
      bh[kt] = *reinterpret_cast<const bf16x8*>(BsB + rbase + ((((kt * 4 + lg) ^ lx)) << 4));

    f32x4 acc = (f32x4){0.f, 0.f, 0.f, 0.f};
#pragma unroll
    for (int kt = 0; kt < 4; ++kt)
      acc = __builtin_amdgcn_mfma_f32_16x16x32_bf16(ah[kt], bh[kt], acc, 0, 0, 0);

    // fused epilogue for these 16 cols (all operands in regs)
    const int col = col0 + fj * 16 + ln;
    const float sjv = sqj[fj];
    const int   ljv = labj[fj];
    const float qv = C_CONST * sjv;
    const float b  = 1.f - qv;
    const float b2 = b * b;
    float cd = 0.f, cp = 0.f, cn = 0.f;
#pragma unroll
    for (int r = 0; r < 4; ++r) {
      const int row = row0 + lg * 4 + r;
      const float g   = acc[r];
      const float pi_ = C_CONST * si[r];
      const float tt  = fmaf(-2.f * C_CONST, g, 1.f);   // 1 - 2Cg
      const float a   = tt + pi_;                       // 1 - 2Cg + C si
      const float den = fabsf(fmaf(pi_, qv, tt));       // |1-2Cg+C^2 si sj|
      float ns = a * a * sjv;
      ns = fmaf(b2, si[r], ns);
      ns = fmaf(-2.f * a * b, g, ns);
      ns = fmaxf(ns, 0.f);
      const float rr = __builtin_amdgcn_sqrtf(C_CONST * ns);
      float ratio = (den - rr) * __builtin_amdgcn_rcpf(den + rr);
      ratio = fmaxf(ratio, RATIO_MIN);
      const float P = __builtin_amdgcn_logf(ratio);     // log2(ratio)
      const float t2 = ratio * ratio;                   // e = ratio^20
      const float t4 = t2 * t2;
      const float t5 = t4 * ratio;
      const float t10 = t5 * t5;
      const float e = t10 * t10;
      const bool mask = row < col;                      // strict upper: once/pair
      const bool same = mask && (ljv == li[r]);
      const float ev = mask ? e : 0.f;
      const float pv = same ? LOGIT_SCALE * P : 0.f;
      const float nv = same ? 1.f : 0.f;
      dacc[r] += ev; pacc[r] += pv; nacc[r] += nv;
      cd += ev; cp += pv; cn += nv;
    }
    // col-side: reduce over the 4 lg groups; per-wave LDS slice
    cd += __shfl_xor(cd, 16); cd += __shfl_xor(cd, 32);
    cp += __shfl_xor(cp, 16); cp += __shfl_xor(cp, 32);
    cn += __shfl_xor(cn, 16); cn += __shfl_xor(cn, 32);
    if (l < 16) {
      colAcc[w][0][fj * 16 + ln] = cd;
      colAcc[w][1][fj * 16 + ln] = cp;
      colAcc[w][2][fj * 16 + ln] = cn;
    }
  }

  // row-side: reduce over the 16 ln lanes -> per-wave LDS slice
#pragma unroll
  for (int r = 0; r < 4; ++r) {
    float d = dacc[r], p = pacc[r], n = nacc[r];
#pragma unroll
    for (int off = 1; off < 16; off <<= 1) {
      d += __shfl_xor(d, off);
      p += __shfl_xor(p, off);
      n += __shfl_xor(n, off);
    }
    if (ln == 0) {
      rowAcc[w][0][lg * 4 + r] = d;
      rowAcc[w][1][lg * 4 + r] = p;
      rowAcc[w][2][lg * 4 + r] = n;
    }
  }

  __syncthreads();

  // unique-writer coalesced partial stores (no atomics, no init needed)
  if (tid < 64) {
    const float rv0 = rowAcc[tid >> 4][0][tid & 15];
    const float rv1 = rowAcc[tid >> 4][1][tid & 15];
    const float rv2 = rowAcc[tid >> 4][2][tid & 15];
    const float cv0 = colAcc[0][0][tid] + colAcc[1][0][tid] + colAcc[2][0][tid] + colAcc[3][0][tid];
    const float cv1 = colAcc[0][1][tid] + colAcc[1][1][tid] + colAcc[2][1][tid] + colAcc[3][1][tid];
    const float cv2 = colAcc[0][2][tid] + colAcc[1][2][tid] + colAcc[2][2][tid] + colAcc[3][2][tid];
    if (bi == bj) {
      const size_t idx = (size_t)bi * B + bi * 64 + tid;
      dpart[idx] = rv0 + cv0;
      ppart[idx] = rv1 + cv1;
      npart[idx] = rv2 + cv2;
    } else {
      const size_t ridx = (size_t)bj * B + bi * 64 + tid;   // row-side
      dpart[ridx] = rv0; ppart[ridx] = rv1; npart[ridx] = rv2;
      const size_t cidx = (size_t)bi * B + bj * 64 + tid;   // col-side
      dpart[cidx] = cv0; ppart[cidx] = cv1; npart[cidx] = cv2;
    }
  }
}

// single finalize kernel: 16 blocks; per-block partial, then the LAST block
// (done-counter, 16 threadfences total -- negligible) reduces the 16 partials.
__global__ __launch_bounds__(256) void finalize_kernel(
    const float* __restrict__ dpart, const float* __restrict__ ppart,
    const float* __restrict__ npart, float* __restrict__ lossP,
    float* __restrict__ validP, unsigned int* __restrict__ cnt,
    float* __restrict__ out, int B) {
  const int tid = threadIdx.x;
  const int i = blockIdx.x * 256 + tid;
  float d = 0.f, p = 0.f, n = 0.f;
#pragma unroll 8
  for (int s = 0; s < NSPLIT; ++s) {
    d += dpart[(size_t)s * B + i];     // coalesced across threads
    p += ppart[(size_t)s * B + i];
    n += npart[(size_t)s * B + i];
  }
  float s_loss = 0.f, s_valid = 0.f;
  if (n > 0.f) {
    float ln_d = __builtin_amdgcn_logf(d) * LN2;
    float rl = -(p - n * ln_d) / n * TEMP;
    if (!(rl != rl)) s_loss = rl;      // NaN -> 0 like reference
    s_valid = 1.f;
  }
#pragma unroll
  for (int off = 1; off < 64; off <<= 1) {
    s_loss += __shfl_xor(s_loss, off);
    s_valid += __shfl_xor(s_valid, off);
  }
  __shared__ float red[8];
  const int wid = tid >> 6;
  if ((tid & 63) == 0) { red[wid] = s_loss; red[wid + 4] = s_valid; }
  __syncthreads();
  if (tid == 0) {
    lossP[blockIdx.x]  = red[0] + red[1] + red[2] + red[3];
    validP[blockIdx.x] = red[4] + red[5] + red[6] + red[7];
  }

  // last-block final reduce (r14 pattern; correctness-proven, cheap at 16 blocks)
  __threadfence();
  __shared__ unsigned int lastFlag;
  if (tid == 0)
    lastFlag = (atomicAdd(cnt, 1u) == (unsigned)(FBLK - 1)) ? 1u : 0u;
  __syncthreads();
  if (lastFlag != 0u && tid < 64) {
    float L = 0.f, V = 0.f;
    if (tid < FBLK) {
      L = __hip_atomic_load(&lossP[tid],  __ATOMIC_RELAXED, __HIP_MEMORY_SCOPE_AGENT);
      V = __hip_atomic_load(&validP[tid], __ATOMIC_RELAXED, __HIP_MEMORY_SCOPE_AGENT);
    }
#pragma unroll
    for (int off = 1; off < 64; off <<= 1) {
      L += __shfl_xor(L, off);
      V += __shfl_xor(V, off);
    }
    if (tid == 0) out[0] = L / fmaxf(V, 1.f);
  }
}

extern "C" void kernel_launch(void* const* d_in, const int* in_sizes, int n_in,
                              void* d_out, int out_size, void* d_ws, size_t ws_size,
                              hipStream_t stream) {
  const float* F = (const float*)d_in[0];
  const int* labels = (const int*)d_in[1];
  const int B = in_sizes[1];           // 4096

  float* sq    = (float*)d_ws;
  float* dpart = sq + B;
  float* ppart = dpart + (size_t)NSPLIT * B;
  float* npart = ppart + (size_t)NSPLIT * B;
  float* lossP = npart + (size_t)NSPLIT * B;
  float* validP = lossP + FBLK;
  unsigned int* cnt = (unsigned int*)(validP + FBLK);
  __bf16* Fh = (__bf16*)(cnt + 64);    // 256B-aligned pad

  const int nt = B / 64;                 // 64
  const int nblocks = nt * (nt + 1) / 2; // 2080

  prep_kernel<<<dim3(B / 8), dim3(256), 0, stream>>>(F, Fh, sq, cnt);
  gram_kernel<<<dim3(nblocks), dim3(256), 0, stream>>>(
      Fh, sq, labels, dpart, ppart, npart, B, nt);
  finalize_kernel<<<dim3(FBLK), dim3(256), 0, stream>>>(
      dpart, ppart, npart, lossP, validP, cnt, (float*)d_out, B);
}

// Round 19
// 33.976 us; speedup vs baseline: 1.0367x; 1.0367x over previous
//
#include <hip/hip_runtime.h>
#include <cstddef>

// Hyperbolic supervised contrastive loss, fused, MFMA bf16 Gram, symmetric.
// G ~= bf16(F) bf16(F)^T (validated r12-r18, absmax 0.0 vs threshold 9.4e-2).
// logits_max cancels (softmax shift invariance).
// EPILOGUE IDENTITY (r19, verified symbolically + numerically):
//   num_sq = a^2*sj - 2ab*g + b^2*si  ==  (si + sj - 2g) * den
//   with den = 1 - 2Cg + C^2*si*sj  (>= (1-C*sqrt(si*sj))^2 >= 0 by C-S)
// -> per-pair: den, dd = si+sj-2g, ns = max(dd*den,0), r = sqrt(C*ns),
//    ratio = (|den|-r)/(|den|+r). Saves ~5 VALU/pair + shortens the chain.
// r16/r17 lesson: launch_bounds waves-arg is a VGPR cap -- (256,8) = 64 VGPR
// -> 143 MB scratch spill; (256,4) = 128 VGPR cap -> spill-free.
// NO GLOBAL ATOMICS in gram: wedge gives every (split,row) a unique writer:
//   entry (s, r), br=r/64:  br<s -> block (br,s) row-side
//                           br>s -> block (s,br) col-side
//                           br==s -> diagonal block stores row+col sum
// 64x64 tiles, triangular wedge bi<=bj (nt=64, 2080 blocks), LDS ~20 KB.
// B-tile 16B-chunk XOR swizzle (c ^= row&7), linear dest + pre-swizzled src.
// Finalize: ONE kernel (16 blocks + done-counter; last block reduces).
// exp(logit) = ratio^20 via 5 mults; logit = 20*ln2*log2(ratio).

typedef __bf16 bf16x8 __attribute__((ext_vector_type(8)));
typedef __bf16 bf16x4 __attribute__((ext_vector_type(4)));
typedef float  f32x4  __attribute__((ext_vector_type(4)));

#define C_CONST 0.01f
#define RATIO_MIN 5.000025e-06f           // ratio at clamp 1-1e-5
#define LOGIT_SCALE 13.86294361119890619f // 20*ln(2)
#define TEMP 0.5f
#define LN2 0.69314718055994530942f
constexpr int DD = 128;
constexpr int NSPLIT = 64;                // = nt
constexpr int FBLK = 16;

// bf16 convert + row squared-norms + zero done-counter. 8 rows/block.
__global__ __launch_bounds__(256) void prep_kernel(
    const float* __restrict__ F, __bf16* __restrict__ Fh, float* __restrict__ sq,
    unsigned int* __restrict__ cnt) {
  const int tid = threadIdx.x;
  const int lane = tid & 31;
  const int row = blockIdx.x * 8 + (tid >> 5);
  if (blockIdx.x == 0 && tid == 0) *cnt = 0u;
  const float4 v = *reinterpret_cast<const float4*>(F + (size_t)row * DD + lane * 4);
  float s = v.x * v.x + v.y * v.y + v.z * v.z + v.w * v.w;
  bf16x4 h;
  h[0] = (__bf16)v.x; h[1] = (__bf16)v.y; h[2] = (__bf16)v.z; h[3] = (__bf16)v.w;
  *reinterpret_cast<bf16x4*>(Fh + (size_t)row * DD + lane * 4) = h;
#pragma unroll
  for (int off = 1; off < 32; off <<= 1) s += __shfl_xor(s, off);
  if (lane == 0) sq[row] = s;
}

// 64x64 tile; 4 waves, wave w owns rows row0..row0+15 (1 row-frag x 4 col-frags).
// C/D layout (verified m89): value r of frag fj at
// row = row0 + lg*4 + r, col = col0 + fj*16 + ln.
__global__ __launch_bounds__(256, 4) void gram_kernel(
    const __bf16* __restrict__ Fh,
    const float* __restrict__ sq, const int* __restrict__ labels,
    float* __restrict__ dpart, float* __restrict__ ppart, float* __restrict__ npart,
    int B, int nt) {
  __shared__ __bf16 Bs[64 * 128];           // 16 KB B-tile, chunk-XOR swizzle
  __shared__ float colAcc[4][3][64];        // per-wave col-side slices (3 KB)
  __shared__ float rowAcc[4][3][16];        // per-wave row-side slices (768 B)
  char* BsB = reinterpret_cast<char*>(Bs);

  const int tid = threadIdx.x;
  const int l  = tid & 63;
  const int w  = tid >> 6;
  const int lg = l >> 4, ln = l & 15;
  const int lx = ln & 7;

  // triangular decode: block t -> (bi, bj), bi <= bj. S(bi) = bi*nt - bi(bi-1)/2
  const int t = blockIdx.x;
  int bi = (int)((2 * nt + 1 - sqrtf((float)((2 * nt + 1) * (2 * nt + 1) - 8 * t))) * 0.5f);
  while ((bi + 1) * nt - ((bi + 1) * bi) / 2 <= t) ++bi;
  while (bi * nt - (bi * (bi - 1)) / 2 > t) --bi;
  const int bj = bi + (t - (bi * nt - (bi * (bi - 1)) / 2));

  const int row0 = bi * 64 + w * 16;
  const int col0 = bj * 64;

  // --- stage B tile (64 rows x 128 dims) into LDS: linear dest, pre-swizzled src
  // LDS chunk k (16B) of row r holds global chunk ((k&15) ^ (r&7)) of row r.
#pragma unroll
  for (int j = 0; j < 4; ++j) {
    const int k = tid + j * 256;            // chunk id 0..1023
    const int row = k >> 4;
    const int cc = (k & 15) ^ (row & 7);
    bf16x8 v = *reinterpret_cast<const bf16x8*>(Fh + (size_t)(col0 + row) * DD + cc * 8);
    *reinterpret_cast<bf16x8*>(BsB + (size_t)k * 16) = v;
  }

  // --- A fragments to regs (16 VGPR)
  const __bf16* Ahp = Fh + (size_t)(row0 + ln) * DD + lg * 8;
  bf16x8 ah[4];
#pragma unroll
  for (int kt = 0; kt < 4; ++kt)
    ah[kt] = *reinterpret_cast<const bf16x8*>(Ahp + kt * 32);

  // --- row/col metadata hoisted pre-barrier
  float si[4], c2si[4]; int li[4];
#pragma unroll
  for (int r = 0; r < 4; ++r) {
    const int row = row0 + lg * 4 + r;
    si[r] = sq[row];
    c2si[r] = (C_CONST * C_CONST) * si[r];
    li[r] = labels[row];
  }
  float sqj[4]; int labj[4];
#pragma unroll
  for (int fj = 0; fj < 4; ++fj) {
    sqj[fj]  = sq[col0 + fj * 16 + ln];
    labj[fj] = labels[col0 + fj * 16 + ln];
  }

  __syncthreads();

  float dacc[4] = {}, pacc[4] = {}, nacc[4] = {};

#pragma unroll
  for (int fj = 0; fj < 4; ++fj) {
    // 4 ds_read_b128 (swizzled)
    const int rbase = (fj * 16 + ln) * 256;
    bf16x8 bh[4];
#pragma unroll
    for (int kt = 0; kt < 4; ++kt)
      bh[kt] = *reinterpret_cast<const bf16x8*>(BsB + rbase + ((((kt * 4 + lg) ^ lx)) << 4));

    f32x4 acc = (f32x4){0.f, 0.f, 0.f, 0.f};
#pragma unroll
    for (int kt = 0; kt < 4; ++kt)
      acc = __builtin_amdgcn_mfma_f32_16x16x32_bf16(ah[kt], bh[kt], acc, 0, 0, 0);

    // fused epilogue for these 16 cols (identity-simplified form)
    const int col = col0 + fj * 16 + ln;
    const float sjv = sqj[fj];
    const int   ljv = labj[fj];
    float sums[4];
#pragma unroll
    for (int r = 0; r < 4; ++r) sums[r] = si[r] + sjv;
    float cd = 0.f, cp = 0.f, cn = 0.f;
#pragma unroll
    for (int r = 0; r < 4; ++r) {
      const int row = row0 + lg * 4 + r;
      const float g   = acc[r];
      const float tt  = fmaf(-2.f * C_CONST, g, 1.f);   // 1 - 2Cg
      const float den = fmaf(c2si[r], sjv, tt);         // 1 - 2Cg + C^2 si sj  (>=0)
      const float dd  = fmaf(-2.f, g, sums[r]);         // si + sj - 2g = |xi-xj|^2
      const float ns  = fmaxf(dd * den, 0.f);           // num_sq = dd*den (identity)
      const float rr  = __builtin_amdgcn_sqrtf(C_CONST * ns);
      const float dA  = fabsf(den);
      float ratio = (dA - rr) * __builtin_amdgcn_rcpf(dA + rr);
      ratio = fmaxf(ratio, RATIO_MIN);
      const float P = __builtin_amdgcn_logf(ratio);     // log2(ratio)
      const float t2 = ratio * ratio;                   // e = ratio^20
      const float t4 = t2 * t2;
      const float t5 = t4 * ratio;
      const float t10 = t5 * t5;
      const float e = t10 * t10;
      const bool mask = row < col;                      // strict upper: once/pair
      const bool same = mask && (ljv == li[r]);
      const float ev = mask ? e : 0.f;
      const float pv = same ? LOGIT_SCALE * P : 0.f;
      const float nv = same ? 1.f : 0.f;
      dacc[r] += ev; pacc[r] += pv; nacc[r] += nv;
      cd += ev; cp += pv; cn += nv;
    }
    // col-side: reduce over the 4 lg groups; per-wave LDS slice
    cd += __shfl_xor(cd, 16); cd += __shfl_xor(cd, 32);
    cp += __shfl_xor(cp, 16); cp += __shfl_xor(cp, 32);
    cn += __shfl_xor(cn, 16); cn += __shfl_xor(cn, 32);
    if (l < 16) {
      colAcc[w][0][fj * 16 + ln] = cd;
      colAcc[w][1][fj * 16 + ln] = cp;
      colAcc[w][2][fj * 16 + ln] = cn;
    }
  }

  // row-side: reduce over the 16 ln lanes -> per-wave LDS slice
#pragma unroll
  for (int r = 0; r < 4; ++r) {
    float d = dacc[r], p = pacc[r], n = nacc[r];
#pragma unroll
    for (int off = 1; off < 16; off <<= 1) {
      d += __shfl_xor(d, off);
      p += __shfl_xor(p, off);
      n += __shfl_xor(n, off);
    }
    if (ln == 0) {
      rowAcc[w][0][lg * 4 + r] = d;
      rowAcc[w][1][lg * 4 + r] = p;
      rowAcc[w][2][lg * 4 + r] = n;
    }
  }

  __syncthreads();

  // unique-writer coalesced partial stores (no atomics, no init needed)
  if (tid < 64) {
    const float rv0 = rowAcc[tid >> 4][0][tid & 15];
    const float rv1 = rowAcc[tid >> 4][1][tid & 15];
    const float rv2 = rowAcc[tid >> 4][2][tid & 15];
    const float cv0 = colAcc[0][0][tid] + colAcc[1][0][tid] + colAcc[2][0][tid] + colAcc[3][0][tid];
    const float cv1 = colAcc[0][1][tid] + colAcc[1][1][tid] + colAcc[2][1][tid] + colAcc[3][1][tid];
    const float cv2 = colAcc[0][2][tid] + colAcc[1][2][tid] + colAcc[2][2][tid] + colAcc[3][2][tid];
    if (bi == bj) {
      const size_t idx = (size_t)bi * B + bi * 64 + tid;
      dpart[idx] = rv0 + cv0;
      ppart[idx] = rv1 + cv1;
      npart[idx] = rv2 + cv2;
    } else {
      const size_t ridx = (size_t)bj * B + bi * 64 + tid;   // row-side
      dpart[ridx] = rv0; ppart[ridx] = rv1; npart[ridx] = rv2;
      const size_t cidx = (size_t)bi * B + bj * 64 + tid;   // col-side
      dpart[cidx] = cv0; ppart[cidx] = cv1; npart[cidx] = cv2;
    }
  }
}

// single finalize kernel: 16 blocks; per-block partial, then the LAST block
// (done-counter, 16 threadfences total -- negligible) reduces the 16 partials.
__global__ __launch_bounds__(256) void finalize_kernel(
    const float* __restrict__ dpart, const float* __restrict__ ppart,
    const float* __restrict__ npart, float* __restrict__ lossP,
    float* __restrict__ validP, unsigned int* __restrict__ cnt,
    float* __restrict__ out, int B) {
  const int tid = threadIdx.x;
  const int i = blockIdx.x * 256 + tid;
  float d = 0.f, p = 0.f, n = 0.f;
#pragma unroll 8
  for (int s = 0; s < NSPLIT; ++s) {
    d += dpart[(size_t)s * B + i];     // coalesced across threads
    p += ppart[(size_t)s * B + i];
    n += npart[(size_t)s * B + i];
  }
  float s_loss = 0.f, s_valid = 0.f;
  if (n > 0.f) {
    float ln_d = __builtin_amdgcn_logf(d) * LN2;
    float rl = -(p - n * ln_d) / n * TEMP;
    if (!(rl != rl)) s_loss = rl;      // NaN -> 0 like reference
    s_valid = 1.f;
  }
#pragma unroll
  for (int off = 1; off < 64; off <<= 1) {
    s_loss += __shfl_xor(s_loss, off);
    s_valid += __shfl_xor(s_valid, off);
  }
  __shared__ float red[8];
  const int wid = tid >> 6;
  if ((tid & 63) == 0) { red[wid] = s_loss; red[wid + 4] = s_valid; }
  __syncthreads();
  if (tid == 0) {
    lossP[blockIdx.x]  = red[0] + red[1] + red[2] + red[3];
    validP[blockIdx.x] = red[4] + red[5] + red[6] + red[7];
  }

  // last-block final reduce (16 threadfences total -- negligible)
  __threadfence();
  __shared__ unsigned int lastFlag;
  if (tid == 0)
    lastFlag = (atomicAdd(cnt, 1u) == (unsigned)(FBLK - 1)) ? 1u : 0u;
  __syncthreads();
  if (lastFlag != 0u && tid < 64) {
    float L = 0.f, V = 0.f;
    if (tid < FBLK) {
      L = __hip_atomic_load(&lossP[tid],  __ATOMIC_RELAXED, __HIP_MEMORY_SCOPE_AGENT);
      V = __hip_atomic_load(&validP[tid], __ATOMIC_RELAXED, __HIP_MEMORY_SCOPE_AGENT);
    }
#pragma unroll
    for (int off = 1; off < 64; off <<= 1) {
      L += __shfl_xor(L, off);
      V += __shfl_xor(V, off);
    }
    if (tid == 0) out[0] = L / fmaxf(V, 1.f);
  }
}

extern "C" void kernel_launch(void* const* d_in, const int* in_sizes, int n_in,
                              void* d_out, int out_size, void* d_ws, size_t ws_size,
                              hipStream_t stream) {
  const float* F = (const float*)d_in[0];
  const int* labels = (const int*)d_in[1];
  const int B = in_sizes[1];           // 4096

  float* sq    = (float*)d_ws;
  float* dpart = sq + B;
  float* ppart = dpart + (size_t)NSPLIT * B;
  float* npart = ppart + (size_t)NSPLIT * B;
  float* lossP = npart + (size_t)NSPLIT * B;
  float* validP = lossP + FBLK;
  unsigned int* cnt = (unsigned int*)(validP + FBLK);
  __bf16* Fh = (__bf16*)(cnt + 64);    // 256B-aligned pad

  const int nt = B / 64;                 // 64
  const int nblocks = nt * (nt + 1) / 2; // 2080

  prep_kernel<<<dim3(B / 8), dim3(256), 0, stream>>>(F, Fh, sq, cnt);
  gram_kernel<<<dim3(nblocks), dim3(256), 0, stream>>>(
      Fh, sq, labels, dpart, ppart, npart, B, nt);
  finalize_kernel<<<dim3(FBLK), dim3(256), 0, stream>>>(
      dpart, ppart, npart, lossP, validP, cnt, (float*)d_out, B);
}